// Round 6
// baseline (641.300 us; speedup 1.0000x reference)
//
#include <hip/hip_runtime.h>
#include <math.h>

typedef __attribute__((ext_vector_type(8))) short short8;
typedef __attribute__((ext_vector_type(4))) float f32x4;

#define B_TOT   65536
#define ROWS    32
#define NBLK    (B_TOT / ROWS)      // 2048
#define THREADS 1024
#define LOG2PI_F 1.8378770664093453f
#define HALF_N_LOG2PI (0.5f * 64.0f * LOG2PI_F)
#define LOG_1EM8 (-18.420680743952367f)

// ws layout (bytes)
#define WS_W2HI 0
#define WS_W2LO (2*1024*1024)
#define WS_W1HI (4*1024*1024)
#define WS_W1LO (WS_W1HI + 128*1024)
#define WS_PART (WS_W1LO + 128*1024)

__device__ __forceinline__ void split_bf16(float a, unsigned short& hi, unsigned short& lo) {
    unsigned u = __float_as_uint(a);
    unsigned r = u + 0x7FFFu + ((u >> 16) & 1u);
    hi = (unsigned short)(r >> 16);
    float fhi = __uint_as_float(((unsigned)hi) << 16);
    float fl = a - fhi;
    unsigned v = __float_as_uint(fl);
    unsigned s = v + 0x7FFFu + ((v >> 16) & 1u);
    lo = (unsigned short)(s >> 16);
}

__device__ __forceinline__ float eluf(float v) {
    return v > 0.0f ? v : expm1f(v);
}

// src fp32 [Kd][1024] -> dHi/dLo bf16 packed [(Kd/32)][1024 n][32 k]
__global__ __launch_bounds__(256)
void pack_split(const float* __restrict__ src, unsigned short* __restrict__ dHi,
                unsigned short* __restrict__ dLo, int Kd)
{
    __shared__ float ts[64][65];
    const int t = threadIdx.x;
    const int k0 = blockIdx.x * 64, n0 = blockIdx.y * 64;
    {
        int r = t >> 2, c4 = t & 3;
        for (int i = 0; i < 4; ++i) {
            int cc = i * 4 + c4;
            float4 v = *(const float4*)&src[(size_t)(k0 + r) * 1024 + n0 + cc * 4];
            ts[r][cc*4+0] = v.x; ts[r][cc*4+1] = v.y;
            ts[r][cc*4+2] = v.z; ts[r][cc*4+3] = v.w;
        }
    }
    __syncthreads();
    {
        int n = t >> 2;
        for (int i = 0; i < 4; ++i) {
            int kk = (i * 4 + (t & 3)) * 4;      // 0..60, 4-aligned
            int k = k0 + kk;
            ushort4 h, l;
            split_bf16(ts[kk+0][n], h.x, l.x);
            split_bf16(ts[kk+1][n], h.y, l.y);
            split_bf16(ts[kk+2][n], h.z, l.z);
            split_bf16(ts[kk+3][n], h.w, l.w);
            size_t off = (size_t)(k >> 5) * 32768 + (size_t)(n0 + n) * 32 + (k & 31);
            *(ushort4*)&dHi[off] = h;
            *(ushort4*)&dLo[off] = l;
        }
    }
}

__global__ __launch_bounds__(THREADS, 4)   // cap VGPR at 128: LDS pins us to 1 block/CU anyway
void fused_mdn(const float* __restrict__ x, const float* __restrict__ y,
               const unsigned short* __restrict__ W1P_hi, const unsigned short* __restrict__ W1P_lo,
               const float* __restrict__ b1,
               const unsigned short* __restrict__ W2P_hi, const unsigned short* __restrict__ W2P_lo,
               const float* __restrict__ b2,
               const float* __restrict__ Wp1, const float* __restrict__ bp1,
               const float* __restrict__ Wp2, const float* __restrict__ bp2,
               float* __restrict__ partials)
{
    __shared__ __align__(16) unsigned short hsu[2][ROWS * 1024]; // 128 KB: h hi/lo; first half reused as iv
    __shared__ __align__(16) float scAB[4096];                   // 16 KB: [0:2048) xs hi/lo, [2048:4096) xp
    __shared__ float lps[256];        // lp[(gg*8+j)*8 + k']
    __shared__ float vrs[256];        // vrsum[row][j]
    __shared__ float lses[ROWS];

    const int t   = threadIdx.x;
    const int q   = blockIdx.x;
    const int w   = t >> 6;      // 0..15, wave owns cols [w*64, w*64+64)
    const int l   = t & 63;
    const int g   = l >> 4;
    const int l15 = l & 15;

    unsigned short* xs_hi = (unsigned short*)scAB;   // [32][64] swizzled
    unsigned short* xs_lo = xs_hi + 2048;

    // ---------- phase 0: stage x rows [32q,32q+32), split hi/lo, swizzled ----------
    if (t < 512) {
        const float4* x4 = (const float4*)x;
        int r = t >> 4, c = t & 15;
        float4 v = x4[(size_t)(q * ROWS + r) * 16 + c];
        float vv[4] = {v.x, v.y, v.z, v.w};
        #pragma unroll
        for (int i = 0; i < 4; ++i) {
            int col = c * 4 + i;
            unsigned short hi, lo;
            split_bf16(vv[i], hi, lo);
            int idx = r * 64 + (col ^ ((r & 7) << 3));
            xs_hi[idx] = hi; xs_lo[idx] = lo;
        }
    }
    __syncthreads();

    f32x4 acc[2][4];

    // ---------- phase 1: h = elu(x @ W1 + b1) ----------
    #pragma unroll
    for (int ct = 0; ct < 4; ++ct) {
        float bv = b1[w * 64 + ct * 16 + l15];
        acc[0][ct] = (f32x4){bv, bv, bv, bv};
        acc[1][ct] = (f32x4){bv, bv, bv, bv};
    }
    #pragma unroll
    for (int k0 = 0; k0 < 64; k0 += 32) {
        short8 bH[4], bL[4];
        #pragma unroll
        for (int ct = 0; ct < 4; ++ct) {
            int n = w * 64 + ct * 16 + l15;
            size_t off = (size_t)(k0 >> 5) * 32768 + (size_t)n * 32 + 8 * g;
            bH[ct] = *(const short8*)&W1P_hi[off];
            bL[ct] = *(const short8*)&W1P_lo[off];
        }
        short8 aH[2], aL[2];
        #pragma unroll
        for (int rt = 0; rt < 2; ++rt) {
            int row = rt * 16 + l15;
            int cidx = row * 64 + ((k0 + 8 * g) ^ ((row & 7) << 3));
            aH[rt] = *(const short8*)&xs_hi[cidx];
            aL[rt] = *(const short8*)&xs_lo[cidx];
        }
        #pragma unroll
        for (int ct = 0; ct < 4; ++ct)
            #pragma unroll
            for (int rt = 0; rt < 2; ++rt) {
                acc[rt][ct] = __builtin_amdgcn_mfma_f32_16x16x32_bf16(aH[rt], bH[ct], acc[rt][ct], 0, 0, 0);
                acc[rt][ct] = __builtin_amdgcn_mfma_f32_16x16x32_bf16(aH[rt], bL[ct], acc[rt][ct], 0, 0, 0);
                acc[rt][ct] = __builtin_amdgcn_mfma_f32_16x16x32_bf16(aL[rt], bH[ct], acc[rt][ct], 0, 0, 0);
            }
    }
    // epilogue: ELU, split, write h hi/lo into hsu (swizzled)
    #pragma unroll
    for (int rt = 0; rt < 2; ++rt)
        #pragma unroll
        for (int ct = 0; ct < 4; ++ct)
            #pragma unroll
            for (int rg = 0; rg < 4; ++rg) {
                float v = eluf(acc[rt][ct][rg]);
                int row = rt * 16 + 4 * g + rg;
                int col = w * 64 + ct * 16 + l15;
                unsigned short hi, lo;
                split_bf16(v, hi, lo);
                int idx = row * 1024 + (col ^ ((row & 7) << 3));
                hsu[0][idx] = hi; hsu[1][idx] = lo;
            }
    // stage xp rows (the 32 outputs' x-rows) into scAB[2048:4096) — dead region until phase 4
    if (t < 512) {
        const float4* x4 = (const float4*)x;
        int o = t >> 4, c = t & 15;
        int bprime = 4 * q + (o >> 3) + (o & 7) * 8192;
        ((float4*)(scAB + 2048))[o * 16 + c] = x4[(size_t)bprime * 16 + c];
    }
    __syncthreads();

    // ---------- phase 2: fhatx = h @ W2 + b2 (2-deep B prefetch pipeline) ----------
    #pragma unroll
    for (int ct = 0; ct < 4; ++ct) {
        float bv = b2[w * 64 + ct * 16 + l15];
        acc[0][ct] = (f32x4){bv, bv, bv, bv};
        acc[1][ct] = (f32x4){bv, bv, bv, bv};
    }
    const unsigned short* hhi = hsu[0];
    const unsigned short* hlo = hsu[1];
    size_t boff[4];
    #pragma unroll
    for (int ct = 0; ct < 4; ++ct) {
        int n = w * 64 + ct * 16 + l15;
        boff[ct] = (size_t)n * 32 + 8 * g;
    }
    short8 bHc[4], bLc[4];
    #pragma unroll
    for (int ct = 0; ct < 4; ++ct) {
        bHc[ct] = *(const short8*)&W2P_hi[boff[ct]];
        bLc[ct] = *(const short8*)&W2P_lo[boff[ct]];
    }
    #pragma unroll 2
    for (int k0 = 0; k0 < 1024; k0 += 32) {
        short8 bHn[4], bLn[4];
        if (k0 + 32 < 1024) {
            size_t base = (size_t)((k0 >> 5) + 1) * 32768;
            #pragma unroll
            for (int ct = 0; ct < 4; ++ct) {
                bHn[ct] = *(const short8*)&W2P_hi[base + boff[ct]];
                bLn[ct] = *(const short8*)&W2P_lo[base + boff[ct]];
            }
        }
        short8 aH[2], aL[2];
        #pragma unroll
        for (int rt = 0; rt < 2; ++rt) {
            int row = rt * 16 + l15;
            int cidx = row * 1024 + ((k0 + 8 * g) ^ ((row & 7) << 3));
            aH[rt] = *(const short8*)&hhi[cidx];
            aL[rt] = *(const short8*)&hlo[cidx];
        }
        #pragma unroll
        for (int ct = 0; ct < 4; ++ct)
            #pragma unroll
            for (int rt = 0; rt < 2; ++rt) {
                acc[rt][ct] = __builtin_amdgcn_mfma_f32_16x16x32_bf16(aH[rt], bHc[ct], acc[rt][ct], 0, 0, 0);
                acc[rt][ct] = __builtin_amdgcn_mfma_f32_16x16x32_bf16(aH[rt], bLc[ct], acc[rt][ct], 0, 0, 0);
                acc[rt][ct] = __builtin_amdgcn_mfma_f32_16x16x32_bf16(aL[rt], bHc[ct], acc[rt][ct], 0, 0, 0);
            }
        if (k0 + 32 < 1024) {
            #pragma unroll
            for (int ct = 0; ct < 4; ++ct) { bHc[ct] = bHn[ct]; bLc[ct] = bLn[ct]; }
        }
    }
    __syncthreads();   // all h reads done; hsu[0] region becomes iv

    // ---------- phase 3: MDN log-prob, fully in-register ----------
    // wave w<8 holds mu[rows 0:32][mix=w][n 0:64]; wave w>=8 holds vr for mix w-8.
    const int j = w & 7;
    float* iv_lds = (float*)hsu;     // [8 mix][32 row][64 n] fp32 = 64 KB

    if (w >= 8) {
        // inverse-variance to LDS + row-sum of log-var
        float rowsum[2][4];
        #pragma unroll
        for (int rt = 0; rt < 2; ++rt)
            #pragma unroll
            for (int rg = 0; rg < 4; ++rg) rowsum[rt][rg] = 0.0f;
        #pragma unroll
        for (int rt = 0; rt < 2; ++rt)
            #pragma unroll
            for (int ct = 0; ct < 4; ++ct)
                #pragma unroll
                for (int rg = 0; rg < 4; ++rg) {
                    float vr = acc[rt][ct][rg];
                    float vre = fmaxf(vr, LOG_1EM8);
                    float iv = (vr >= LOG_1EM8) ? expf(-vr) : 1e8f;
                    rowsum[rt][rg] += vre;
                    int row = rt * 16 + 4 * g + rg;
                    int nw = (ct * 16 + l15) ^ ((g & 1) << 4);
                    iv_lds[(j * 32 + row) * 64 + nw] = iv;
                }
        #pragma unroll
        for (int rt = 0; rt < 2; ++rt)
            #pragma unroll
            for (int rg = 0; rg < 4; ++rg) {
                float s = rowsum[rt][rg];
                s += __shfl_xor(s, 1); s += __shfl_xor(s, 2);
                s += __shfl_xor(s, 4); s += __shfl_xor(s, 8);
                rowsum[rt][rg] = s;
            }
        if (l15 == 0) {
            #pragma unroll
            for (int rt = 0; rt < 2; ++rt)
                #pragma unroll
                for (int rg = 0; rg < 4; ++rg) {
                    int row = rt * 16 + 4 * g + rg;
                    vrs[row * 8 + j] = rowsum[rt][rg];
                }
        }
    } else {
        // mu-wave: load y and form d = y - mu (overlaps var-waves' exp work)
        #pragma unroll
        for (int rt = 0; rt < 2; ++rt)
            #pragma unroll
            for (int ct = 0; ct < 4; ++ct)
                #pragma unroll
                for (int rg = 0; rg < 4; ++rg) {
                    int row = rt * 16 + 4 * g + rg;
                    int bprime = 4 * q + (row >> 3) + j * 8192;
                    float yv = y[(size_t)bprime * 64 + ct * 16 + l15];
                    acc[rt][ct][rg] = yv - acc[rt][ct][rg];
                }
    }
    __syncthreads();

    if (w < 8) {
        float rowsum[2][4];
        #pragma unroll
        for (int rt = 0; rt < 2; ++rt)
            #pragma unroll
            for (int rg = 0; rg < 4; ++rg) rowsum[rt][rg] = 0.0f;
        #pragma unroll
        for (int rt = 0; rt < 2; ++rt)
            #pragma unroll
            for (int ct = 0; ct < 4; ++ct)
                #pragma unroll
                for (int rg = 0; rg < 4; ++rg) {
                    int row = rt * 16 + 4 * g + rg;
                    int nw = (ct * 16 + l15) ^ ((g & 1) << 4);
                    float iv = iv_lds[(j * 32 + row) * 64 + nw];
                    float d = acc[rt][ct][rg];
                    rowsum[rt][rg] = fmaf(d * d, iv, rowsum[rt][rg]);
                }
        #pragma unroll
        for (int rt = 0; rt < 2; ++rt)
            #pragma unroll
            for (int rg = 0; rg < 4; ++rg) {
                float s = rowsum[rt][rg];
                s += __shfl_xor(s, 1); s += __shfl_xor(s, 2);
                s += __shfl_xor(s, 4); s += __shfl_xor(s, 8);
                rowsum[rt][rg] = s;
            }
        if (l15 == 0) {
            #pragma unroll
            for (int rt = 0; rt < 2; ++rt)
                #pragma unroll
                for (int rg = 0; rg < 4; ++rg) {
                    int row = rt * 16 + 4 * g + rg;
                    float lp = -0.5f * (rowsum[rt][rg] + vrs[row * 8 + j]) - HALF_N_LOG2PI;
                    lps[((row >> 3) * 8 + j) * 8 + (row & 7)] = lp;
                }
        }
    }
    __syncthreads();

    // ---------- phase 4: pi network ----------
    float* scA = scAB + 2048;   // [32][64] xp (staged after phase 1)
    float* scB = scAB;          // [32][64] tpi (xs region, dead)
    {
        int c = t & 63, ob = t >> 6;   // ob 0..15, rows {ob, ob+16}
        float a0 = bp1[c], a1 = bp1[c];
        for (int n = 0; n < 64; ++n) {
            float wv = Wp1[n * 64 + c];
            a0 += scA[ob * 64 + n] * wv;
            a1 += scA[(ob + 16) * 64 + n] * wv;
        }
        scB[ob * 64 + c] = eluf(a0);
        scB[(ob + 16) * 64 + c] = eluf(a1);
    }
    __syncthreads();
    if (t < 256) {
        int o = t >> 3, k = t & 7;
        float a = bp2[k];
        for (int n = 0; n < 64; ++n) a += scB[o * 64 + n] * Wp2[n * 8 + k];
        float m = a;
        m = fmaxf(m, __shfl_xor(m, 1));
        m = fmaxf(m, __shfl_xor(m, 2));
        m = fmaxf(m, __shfl_xor(m, 4));
        float e = expf(a - m);
        float sden = e;
        sden += __shfl_xor(sden, 1); sden += __shfl_xor(sden, 2); sden += __shfl_xor(sden, 4);
        float logpi = a - m - logf(sden);
        float v = logpi + lps[o * 8 + k];
        float mv = v;
        mv = fmaxf(mv, __shfl_xor(mv, 1));
        mv = fmaxf(mv, __shfl_xor(mv, 2));
        mv = fmaxf(mv, __shfl_xor(mv, 4));
        float ee = expf(v - mv);
        float ss = ee;
        ss += __shfl_xor(ss, 1); ss += __shfl_xor(ss, 2); ss += __shfl_xor(ss, 4);
        if (k == 0) lses[o] = mv + logf(ss);
    }
    __syncthreads();
    if (t == 0) {
        float p = 0.0f;
        #pragma unroll
        for (int o = 0; o < ROWS; ++o) p += lses[o];
        partials[q] = p;
    }
}

__global__ void reduce_partials(const float* __restrict__ partials, float* __restrict__ out)
{
    __shared__ double red[256];
    int t = threadIdx.x;
    double s = 0.0;
    for (int i = t; i < NBLK; i += 256) s += (double)partials[i];
    red[t] = s;
    __syncthreads();
    for (int w = 128; w > 0; w >>= 1) {
        if (t < w) red[t] += red[t + w];
        __syncthreads();
    }
    if (t == 0) out[0] = (float)(-red[0] / (double)B_TOT);
}

extern "C" void kernel_launch(void* const* d_in, const int* in_sizes, int n_in,
                              void* d_out, int out_size, void* d_ws, size_t ws_size,
                              hipStream_t stream)
{
    const float* x   = (const float*)d_in[0];
    const float* y   = (const float*)d_in[1];
    const float* W1  = (const float*)d_in[2];
    const float* b1  = (const float*)d_in[3];
    const float* W2  = (const float*)d_in[4];
    const float* b2  = (const float*)d_in[5];
    const float* Wp1 = (const float*)d_in[6];
    const float* bp1 = (const float*)d_in[7];
    const float* Wp2 = (const float*)d_in[8];
    const float* bp2 = (const float*)d_in[9];

    char* ws = (char*)d_ws;
    unsigned short* W2P_hi = (unsigned short*)(ws + WS_W2HI);
    unsigned short* W2P_lo = (unsigned short*)(ws + WS_W2LO);
    unsigned short* W1P_hi = (unsigned short*)(ws + WS_W1HI);
    unsigned short* W1P_lo = (unsigned short*)(ws + WS_W1LO);
    float* partials        = (float*)(ws + WS_PART);

    pack_split<<<dim3(16, 16), 256, 0, stream>>>(W2, W2P_hi, W2P_lo, 1024);
    pack_split<<<dim3(1, 16), 256, 0, stream>>>(W1, W1P_hi, W1P_lo, 64);
    fused_mdn<<<NBLK, THREADS, 0, stream>>>(x, y, W1P_hi, W1P_lo, b1, W2P_hi, W2P_lo, b2,
                                            Wp1, bp1, Wp2, bp2, partials);
    reduce_partials<<<1, 256, 0, stream>>>(partials, (float*)d_out);
}

// Round 7
// 558.569 us; speedup vs baseline: 1.1481x; 1.1481x over previous
//
#include <hip/hip_runtime.h>
#include <math.h>

typedef __attribute__((ext_vector_type(8))) _Float16 half8;
typedef __attribute__((ext_vector_type(4))) _Float16 half4;
typedef __attribute__((ext_vector_type(4))) float f32x4;

#define B_TOT   65536
#define ROWS    64
#define NBLK    (B_TOT / ROWS)      // 1024
#define THREADS 1024
#define LOG2PI_F 1.8378770664093453f
#define HALF_N_LOG2PI (0.5f * 64.0f * LOG2PI_F)
#define LOG_1EM8 (-18.420680743952367f)

// ws layout (bytes)
#define WS_W2P  0                    // 2 MB fp16 packed
#define WS_W1P  (2*1024*1024)        // 128 KB fp16 packed
#define WS_PART (WS_W1P + 256*1024)

__device__ __forceinline__ float eluf(float v) {
    return v > 0.0f ? v : expm1f(v);
}

// src fp32 [Kd][1024] -> dst fp16 packed [(Kd/32)][1024 n][32 k]
__global__ __launch_bounds__(256)
void pack_f16(const float* __restrict__ src, _Float16* __restrict__ dst, int Kd)
{
    __shared__ float ts[64][65];
    const int t = threadIdx.x;
    const int k0 = blockIdx.x * 64, n0 = blockIdx.y * 64;
    {
        int r = t >> 2, c4 = t & 3;
        for (int i = 0; i < 4; ++i) {
            int cc = i * 4 + c4;
            float4 v = *(const float4*)&src[(size_t)(k0 + r) * 1024 + n0 + cc * 4];
            ts[r][cc*4+0] = v.x; ts[r][cc*4+1] = v.y;
            ts[r][cc*4+2] = v.z; ts[r][cc*4+3] = v.w;
        }
    }
    __syncthreads();
    {
        int n = t >> 2;
        for (int i = 0; i < 4; ++i) {
            int kk = (i * 4 + (t & 3)) * 4;      // 0..60, 4-aligned
            int k = k0 + kk;
            half4 h;
            h.x = (_Float16)ts[kk+0][n];
            h.y = (_Float16)ts[kk+1][n];
            h.z = (_Float16)ts[kk+2][n];
            h.w = (_Float16)ts[kk+3][n];
            size_t off = (size_t)(k >> 5) * 32768 + (size_t)(n0 + n) * 32 + (k & 31);
            *(half4*)&dst[off] = h;
        }
    }
}

__global__ __launch_bounds__(THREADS, 4)   // cap VGPR at 128; LDS pins 1 block/CU anyway
void fused_mdn(const float* __restrict__ x, const float* __restrict__ y,
               const _Float16* __restrict__ W1P, const float* __restrict__ b1,
               const _Float16* __restrict__ W2P, const float* __restrict__ b2,
               const float* __restrict__ Wp1, const float* __restrict__ bp1,
               const float* __restrict__ Wp2, const float* __restrict__ bp2,
               float* __restrict__ partials)
{
    __shared__ __align__(16) _Float16 hs[ROWS * 1024];  // 128 KB: h fp16 -> iv fp32 -> tpi fp32
    __shared__ __align__(16) float    xp[ROWS * 64];    // 16 KB: pi-x rows
    __shared__ __align__(16) _Float16 xs[ROWS * 64];    // 8 KB: x fp16 swizzled
    __shared__ float lps[ROWS * 8];                     // 2 KB
    __shared__ float vrs[ROWS * 8];                     // 2 KB
    __shared__ float lses[ROWS];                        // 256 B

    const int t   = threadIdx.x;
    const int q   = blockIdx.x;
    const int w   = t >> 6;      // 0..15, wave owns cols [w*64, w*64+64)
    const int l   = t & 63;
    const int g   = l >> 4;
    const int l15 = l & 15;

    // ---------- phase 0: stage x rows (fp16, swizzled) + xp rows ----------
    {
        const float4* x4 = (const float4*)x;
        int r = t >> 4, c = t & 15;
        float4 v = x4[(size_t)(q * ROWS + r) * 16 + c];
        float vv[4] = {v.x, v.y, v.z, v.w};
        #pragma unroll
        for (int i = 0; i < 4; ++i) {
            int col = c * 4 + i;
            xs[r * 64 + (col ^ ((r & 7) << 3))] = (_Float16)vv[i];
        }
        // pi-x rows: output o -> b' = 8q + (o>>3) + (o&7)*8192
        int bprime = 8 * q + (r >> 3) + (r & 7) * 8192;
        ((float4*)xp)[r * 16 + c] = x4[(size_t)bprime * 16 + c];
    }
    __syncthreads();

    f32x4 acc[4][4];

    // ---------- phase 1: h = elu(x @ W1 + b1), fp16 MFMA ----------
    #pragma unroll
    for (int ct = 0; ct < 4; ++ct) {
        float bv = b1[w * 64 + ct * 16 + l15];
        #pragma unroll
        for (int rt = 0; rt < 4; ++rt) acc[rt][ct] = (f32x4){bv, bv, bv, bv};
    }
    #pragma unroll
    for (int k0 = 0; k0 < 64; k0 += 32) {
        half8 bF[4];
        #pragma unroll
        for (int ct = 0; ct < 4; ++ct) {
            size_t off = (size_t)(k0 >> 5) * 32768 + (size_t)(w * 64 + ct * 16 + l15) * 32 + 8 * g;
            bF[ct] = *(const half8*)&W1P[off];
        }
        half8 aF[4];
        #pragma unroll
        for (int rt = 0; rt < 4; ++rt) {
            int row = rt * 16 + l15;
            aF[rt] = *(const half8*)&xs[row * 64 + ((k0 + 8 * g) ^ ((row & 7) << 3))];
        }
        #pragma unroll
        for (int ct = 0; ct < 4; ++ct)
            #pragma unroll
            for (int rt = 0; rt < 4; ++rt)
                acc[rt][ct] = __builtin_amdgcn_mfma_f32_16x16x32_f16(aF[rt], bF[ct], acc[rt][ct], 0, 0, 0);
    }
    // epilogue: ELU -> fp16 -> hs (swizzled)
    #pragma unroll
    for (int rt = 0; rt < 4; ++rt)
        #pragma unroll
        for (int ct = 0; ct < 4; ++ct)
            #pragma unroll
            for (int rg = 0; rg < 4; ++rg) {
                float v = eluf(acc[rt][ct][rg]);
                int row = rt * 16 + 4 * g + rg;
                int col = w * 64 + ct * 16 + l15;
                hs[row * 1024 + (col ^ ((row & 7) << 3))] = (_Float16)v;
            }
    __syncthreads();

    // ---------- phase 2: fhatx = h @ W2 + b2, fp16 MFMA ----------
    #pragma unroll
    for (int ct = 0; ct < 4; ++ct) {
        float bv = b2[w * 64 + ct * 16 + l15];
        #pragma unroll
        for (int rt = 0; rt < 4; ++rt) acc[rt][ct] = (f32x4){bv, bv, bv, bv};
    }
    #pragma unroll 2
    for (int k0 = 0; k0 < 1024; k0 += 32) {
        half8 bF[4];
        #pragma unroll
        for (int ct = 0; ct < 4; ++ct) {
            size_t off = (size_t)(k0 >> 5) * 32768 + (size_t)(w * 64 + ct * 16 + l15) * 32 + 8 * g;
            bF[ct] = *(const half8*)&W2P[off];
        }
        half8 aF[4];
        #pragma unroll
        for (int rt = 0; rt < 4; ++rt) {
            int row = rt * 16 + l15;
            aF[rt] = *(const half8*)&hs[row * 1024 + ((k0 + 8 * g) ^ ((row & 7) << 3))];
        }
        #pragma unroll
        for (int ct = 0; ct < 4; ++ct)
            #pragma unroll
            for (int rt = 0; rt < 4; ++rt)
                acc[rt][ct] = __builtin_amdgcn_mfma_f32_16x16x32_f16(aF[rt], bF[ct], acc[rt][ct], 0, 0, 0);
    }
    __syncthreads();   // all hs reads done; hs region becomes iv (fp32)

    // ---------- phase 3: MDN log-prob, in-register ----------
    // wave w<8: mu[mix j=w][rows 0:64][n 0:64]; wave w>=8: var_raw for mix j=w-8.
    const int j = w & 7;
    float* iv_lds = (float*)hs;     // [8 mix][64 row][64 n] fp32 = 128 KB

    if (w >= 8) {
        float rowsum[4][4];
        #pragma unroll
        for (int rt = 0; rt < 4; ++rt)
            #pragma unroll
            for (int rg = 0; rg < 4; ++rg) rowsum[rt][rg] = 0.0f;
        #pragma unroll
        for (int rt = 0; rt < 4; ++rt)
            #pragma unroll
            for (int ct = 0; ct < 4; ++ct)
                #pragma unroll
                for (int rg = 0; rg < 4; ++rg) {
                    float vr = acc[rt][ct][rg];
                    float vre = fmaxf(vr, LOG_1EM8);
                    float iv = (vr >= LOG_1EM8) ? expf(-vr) : 1e8f;
                    rowsum[rt][rg] += vre;
                    int row = rt * 16 + 4 * g + rg;
                    int nw = (ct * 16 + l15) ^ ((g & 1) << 4);
                    iv_lds[(j * 64 + row) * 64 + nw] = iv;
                }
        #pragma unroll
        for (int rt = 0; rt < 4; ++rt)
            #pragma unroll
            for (int rg = 0; rg < 4; ++rg) {
                float s = rowsum[rt][rg];
                s += __shfl_xor(s, 1); s += __shfl_xor(s, 2);
                s += __shfl_xor(s, 4); s += __shfl_xor(s, 8);
                rowsum[rt][rg] = s;
            }
        if (l15 == 0) {
            #pragma unroll
            for (int rt = 0; rt < 4; ++rt)
                #pragma unroll
                for (int rg = 0; rg < 4; ++rg) {
                    int row = rt * 16 + 4 * g + rg;
                    vrs[row * 8 + j] = rowsum[rt][rg];
                }
        }
    } else {
        // mu-wave: d = y - mu (overlaps var-waves' exp work)
        #pragma unroll
        for (int rt = 0; rt < 4; ++rt)
            #pragma unroll
            for (int ct = 0; ct < 4; ++ct)
                #pragma unroll
                for (int rg = 0; rg < 4; ++rg) {
                    int row = rt * 16 + 4 * g + rg;
                    int bprime = 8 * q + (row >> 3) + j * 8192;
                    float yv = y[(size_t)bprime * 64 + ct * 16 + l15];
                    acc[rt][ct][rg] = yv - acc[rt][ct][rg];
                }
    }
    __syncthreads();

    if (w < 8) {
        float rowsum[4][4];
        #pragma unroll
        for (int rt = 0; rt < 4; ++rt)
            #pragma unroll
            for (int rg = 0; rg < 4; ++rg) rowsum[rt][rg] = 0.0f;
        #pragma unroll
        for (int rt = 0; rt < 4; ++rt)
            #pragma unroll
            for (int ct = 0; ct < 4; ++ct)
                #pragma unroll
                for (int rg = 0; rg < 4; ++rg) {
                    int row = rt * 16 + 4 * g + rg;
                    int nw = (ct * 16 + l15) ^ ((g & 1) << 4);
                    float iv = iv_lds[(j * 64 + row) * 64 + nw];
                    float d = acc[rt][ct][rg];
                    rowsum[rt][rg] = fmaf(d * d, iv, rowsum[rt][rg]);
                }
        #pragma unroll
        for (int rt = 0; rt < 4; ++rt)
            #pragma unroll
            for (int rg = 0; rg < 4; ++rg) {
                float s = rowsum[rt][rg];
                s += __shfl_xor(s, 1); s += __shfl_xor(s, 2);
                s += __shfl_xor(s, 4); s += __shfl_xor(s, 8);
                rowsum[rt][rg] = s;
            }
        if (l15 == 0) {
            #pragma unroll
            for (int rt = 0; rt < 4; ++rt)
                #pragma unroll
                for (int rg = 0; rg < 4; ++rg) {
                    int row = rt * 16 + 4 * g + rg;
                    float lp = -0.5f * (rowsum[rt][rg] + vrs[row * 8 + j]) - HALF_N_LOG2PI;
                    lps[((row >> 3) * 8 + j) * 8 + (row & 7)] = lp;
                }
        }
    }
    __syncthreads();

    // ---------- phase 4: pi network for 64 outputs ----------
    float* tpi = (float*)hs;   // [64][64] fp32 (iv dead)
    {
        int c = t & 63, ob = t >> 6;   // rows {ob, ob+16, ob+32, ob+48}
        float a0 = bp1[c], a1 = a0, a2 = a0, a3 = a0;
        for (int n = 0; n < 64; ++n) {
            float wv = Wp1[n * 64 + c];
            a0 += xp[(ob +  0) * 64 + n] * wv;
            a1 += xp[(ob + 16) * 64 + n] * wv;
            a2 += xp[(ob + 32) * 64 + n] * wv;
            a3 += xp[(ob + 48) * 64 + n] * wv;
        }
        tpi[(ob +  0) * 64 + c] = eluf(a0);
        tpi[(ob + 16) * 64 + c] = eluf(a1);
        tpi[(ob + 32) * 64 + c] = eluf(a2);
        tpi[(ob + 48) * 64 + c] = eluf(a3);
    }
    __syncthreads();
    if (t < 512) {
        int o = t >> 3, k = t & 7;
        float a = bp2[k];
        for (int n = 0; n < 64; ++n) a += tpi[o * 64 + n] * Wp2[n * 8 + k];
        float m = a;
        m = fmaxf(m, __shfl_xor(m, 1));
        m = fmaxf(m, __shfl_xor(m, 2));
        m = fmaxf(m, __shfl_xor(m, 4));
        float e = expf(a - m);
        float sden = e;
        sden += __shfl_xor(sden, 1); sden += __shfl_xor(sden, 2); sden += __shfl_xor(sden, 4);
        float logpi = a - m - logf(sden);
        float v = logpi + lps[o * 8 + k];
        float mv = v;
        mv = fmaxf(mv, __shfl_xor(mv, 1));
        mv = fmaxf(mv, __shfl_xor(mv, 2));
        mv = fmaxf(mv, __shfl_xor(mv, 4));
        float ee = expf(v - mv);
        float ss = ee;
        ss += __shfl_xor(ss, 1); ss += __shfl_xor(ss, 2); ss += __shfl_xor(ss, 4);
        if (k == 0) lses[o] = mv + logf(ss);
    }
    __syncthreads();
    if (t == 0) {
        float p = 0.0f;
        #pragma unroll
        for (int o = 0; o < ROWS; ++o) p += lses[o];
        partials[q] = p;
    }
}

__global__ void reduce_partials(const float* __restrict__ partials, float* __restrict__ out)
{
    __shared__ double red[256];
    int t = threadIdx.x;
    double s = 0.0;
    for (int i = t; i < NBLK; i += 256) s += (double)partials[i];
    red[t] = s;
    __syncthreads();
    for (int w = 128; w > 0; w >>= 1) {
        if (t < w) red[t] += red[t + w];
        __syncthreads();
    }
    if (t == 0) out[0] = (float)(-red[0] / (double)B_TOT);
}

extern "C" void kernel_launch(void* const* d_in, const int* in_sizes, int n_in,
                              void* d_out, int out_size, void* d_ws, size_t ws_size,
                              hipStream_t stream)
{
    const float* x   = (const float*)d_in[0];
    const float* y   = (const float*)d_in[1];
    const float* W1  = (const float*)d_in[2];
    const float* b1  = (const float*)d_in[3];
    const float* W2  = (const float*)d_in[4];
    const float* b2  = (const float*)d_in[5];
    const float* Wp1 = (const float*)d_in[6];
    const float* bp1 = (const float*)d_in[7];
    const float* Wp2 = (const float*)d_in[8];
    const float* bp2 = (const float*)d_in[9];

    char* ws = (char*)d_ws;
    _Float16* W2P = (_Float16*)(ws + WS_W2P);
    _Float16* W1P = (_Float16*)(ws + WS_W1P);
    float* partials = (float*)(ws + WS_PART);

    pack_f16<<<dim3(16, 16), 256, 0, stream>>>(W2, W2P, 1024);
    pack_f16<<<dim3(1, 16), 256, 0, stream>>>(W1, W1P, 64);
    fused_mdn<<<NBLK, THREADS, 0, stream>>>(x, y, W1P, b1, W2P, b2,
                                            Wp1, bp1, Wp2, bp2, partials);
    reduce_partials<<<1, 256, 0, stream>>>(partials, (float*)d_out);
}

// Round 8
// 557.477 us; speedup vs baseline: 1.1504x; 1.0020x over previous
//
#include <hip/hip_runtime.h>
#include <math.h>

typedef __attribute__((ext_vector_type(8))) _Float16 half8;
typedef __attribute__((ext_vector_type(4))) _Float16 half4;
typedef __attribute__((ext_vector_type(4))) float f32x4;

#define B_TOT   65536
#define ROWS    64
#define NBLK    (B_TOT / ROWS)      // 1024
#define THREADS 1024
#define LOG2PI_F 1.8378770664093453f
#define HALF_N_LOG2PI (0.5f * 64.0f * LOG2PI_F)
#define LOG_1EM8 (-18.420680743952367f)

// ws layout (bytes)
#define WS_W2P  0                    // 2 MB fp16 packed
#define WS_W1P  (2*1024*1024)        // 128 KB fp16 packed
#define WS_PART (WS_W1P + 256*1024)

__device__ __forceinline__ float eluf(float v) {
    return v > 0.0f ? v : expm1f(v);
}

// src fp32 [Kd][1024] -> dst fp16 packed [(Kd/32)][1024 n][32 k]
__global__ __launch_bounds__(256)
void pack_f16(const float* __restrict__ src, _Float16* __restrict__ dst, int Kd)
{
    __shared__ float ts[64][65];
    const int t = threadIdx.x;
    const int k0 = blockIdx.x * 64, n0 = blockIdx.y * 64;
    {
        int r = t >> 2, c4 = t & 3;
        for (int i = 0; i < 4; ++i) {
            int cc = i * 4 + c4;
            float4 v = *(const float4*)&src[(size_t)(k0 + r) * 1024 + n0 + cc * 4];
            ts[r][cc*4+0] = v.x; ts[r][cc*4+1] = v.y;
            ts[r][cc*4+2] = v.z; ts[r][cc*4+3] = v.w;
        }
    }
    __syncthreads();
    {
        int n = t >> 2;
        for (int i = 0; i < 4; ++i) {
            int kk = (i * 4 + (t & 3)) * 4;      // 0..60, 4-aligned
            int k = k0 + kk;
            half4 h;
            h.x = (_Float16)ts[kk+0][n];
            h.y = (_Float16)ts[kk+1][n];
            h.z = (_Float16)ts[kk+2][n];
            h.w = (_Float16)ts[kk+3][n];
            size_t off = (size_t)(k >> 5) * 32768 + (size_t)(n0 + n) * 32 + (k & 31);
            *(half4*)&dst[off] = h;
        }
    }
}

// launch_bounds 2nd arg is CUDA-style min BLOCKS/CU on hipcc (measured: (512,2)->128 VGPR,
// (1024,4)->64 VGPR + spill). 1 block/CU => 4 waves/SIMD => VGPR cap 128, no spill.
__global__ __launch_bounds__(THREADS, 1)
void fused_mdn(const float* __restrict__ x, const float* __restrict__ y,
               const _Float16* __restrict__ W1P, const float* __restrict__ b1,
               const _Float16* __restrict__ W2P, const float* __restrict__ b2,
               const float* __restrict__ Wp1, const float* __restrict__ bp1,
               const float* __restrict__ Wp2, const float* __restrict__ bp2,
               float* __restrict__ partials)
{
    __shared__ __align__(16) _Float16 hs[ROWS * 1024];  // 128 KB: h fp16 -> iv fp32 -> tpi fp32
    __shared__ __align__(16) float    xp[ROWS * 64];    // 16 KB: pi-x rows
    __shared__ __align__(16) _Float16 xs[ROWS * 64];    // 8 KB: x fp16 swizzled
    __shared__ float lps[ROWS * 8];                     // 2 KB
    __shared__ float vrs[ROWS * 8];                     // 2 KB
    __shared__ float lses[ROWS];                        // 256 B

    const int t   = threadIdx.x;
    const int q   = blockIdx.x;
    const int w   = t >> 6;      // 0..15, wave owns cols [w*64, w*64+64)
    const int l   = t & 63;
    const int g   = l >> 4;
    const int l15 = l & 15;

    // ---------- phase 0: stage x rows (fp16, swizzled) + xp rows ----------
    {
        const float4* x4 = (const float4*)x;
        int r = t >> 4, c = t & 15;
        float4 v = x4[(size_t)(q * ROWS + r) * 16 + c];
        float vv[4] = {v.x, v.y, v.z, v.w};
        #pragma unroll
        for (int i = 0; i < 4; ++i) {
            int col = c * 4 + i;
            xs[r * 64 + (col ^ ((r & 7) << 3))] = (_Float16)vv[i];
        }
        // pi-x rows: output o -> b' = 8q + (o>>3) + (o&7)*8192
        int bprime = 8 * q + (r >> 3) + (r & 7) * 8192;
        ((float4*)xp)[r * 16 + c] = x4[(size_t)bprime * 16 + c];
    }
    __syncthreads();

    f32x4 acc[4][4];

    // ---------- phase 1: h = elu(x @ W1 + b1), fp16 MFMA ----------
    #pragma unroll
    for (int ct = 0; ct < 4; ++ct) {
        float bv = b1[w * 64 + ct * 16 + l15];
        #pragma unroll
        for (int rt = 0; rt < 4; ++rt) acc[rt][ct] = (f32x4){bv, bv, bv, bv};
    }
    #pragma unroll
    for (int k0 = 0; k0 < 64; k0 += 32) {
        half8 bF[4];
        #pragma unroll
        for (int ct = 0; ct < 4; ++ct) {
            size_t off = (size_t)(k0 >> 5) * 32768 + (size_t)(w * 64 + ct * 16 + l15) * 32 + 8 * g;
            bF[ct] = *(const half8*)&W1P[off];
        }
        half8 aF[4];
        #pragma unroll
        for (int rt = 0; rt < 4; ++rt) {
            int row = rt * 16 + l15;
            aF[rt] = *(const half8*)&xs[row * 64 + ((k0 + 8 * g) ^ ((row & 7) << 3))];
        }
        #pragma unroll
        for (int ct = 0; ct < 4; ++ct)
            #pragma unroll
            for (int rt = 0; rt < 4; ++rt)
                acc[rt][ct] = __builtin_amdgcn_mfma_f32_16x16x32_f16(aF[rt], bF[ct], acc[rt][ct], 0, 0, 0);
    }
    // epilogue: ELU -> fp16 -> hs (swizzled)
    #pragma unroll
    for (int rt = 0; rt < 4; ++rt)
        #pragma unroll
        for (int ct = 0; ct < 4; ++ct)
            #pragma unroll
            for (int rg = 0; rg < 4; ++rg) {
                float v = eluf(acc[rt][ct][rg]);
                int row = rt * 16 + 4 * g + rg;
                int col = w * 64 + ct * 16 + l15;
                hs[row * 1024 + (col ^ ((row & 7) << 3))] = (_Float16)v;
            }
    __syncthreads();

    // ---------- phase 2: fhatx = h @ W2 + b2, fp16 MFMA ----------
    #pragma unroll
    for (int ct = 0; ct < 4; ++ct) {
        float bv = b2[w * 64 + ct * 16 + l15];
        #pragma unroll
        for (int rt = 0; rt < 4; ++rt) acc[rt][ct] = (f32x4){bv, bv, bv, bv};
    }
    #pragma unroll 2
    for (int k0 = 0; k0 < 1024; k0 += 32) {
        half8 bF[4];
        #pragma unroll
        for (int ct = 0; ct < 4; ++ct) {
            size_t off = (size_t)(k0 >> 5) * 32768 + (size_t)(w * 64 + ct * 16 + l15) * 32 + 8 * g;
            bF[ct] = *(const half8*)&W2P[off];
        }
        half8 aF[4];
        #pragma unroll
        for (int rt = 0; rt < 4; ++rt) {
            int row = rt * 16 + l15;
            aF[rt] = *(const half8*)&hs[row * 1024 + ((k0 + 8 * g) ^ ((row & 7) << 3))];
        }
        #pragma unroll
        for (int ct = 0; ct < 4; ++ct)
            #pragma unroll
            for (int rt = 0; rt < 4; ++rt)
                acc[rt][ct] = __builtin_amdgcn_mfma_f32_16x16x32_f16(aF[rt], bF[ct], acc[rt][ct], 0, 0, 0);
    }
    __syncthreads();   // all hs reads done; hs region becomes iv (fp32)

    // ---------- phase 3: MDN log-prob, in-register ----------
    // wave w<8: mu[mix j=w][rows 0:64][n 0:64]; wave w>=8: var_raw for mix j=w-8.
    const int j = w & 7;
    float* iv_lds = (float*)hs;     // [8 mix][64 row][64 n] fp32 = 128 KB

    if (w >= 8) {
        float rowsum[4][4];
        #pragma unroll
        for (int rt = 0; rt < 4; ++rt)
            #pragma unroll
            for (int rg = 0; rg < 4; ++rg) rowsum[rt][rg] = 0.0f;
        #pragma unroll
        for (int rt = 0; rt < 4; ++rt)
            #pragma unroll
            for (int ct = 0; ct < 4; ++ct)
                #pragma unroll
                for (int rg = 0; rg < 4; ++rg) {
                    float vr = acc[rt][ct][rg];
                    float vre = fmaxf(vr, LOG_1EM8);
                    float iv = (vr >= LOG_1EM8) ? expf(-vr) : 1e8f;
                    rowsum[rt][rg] += vre;
                    int row = rt * 16 + 4 * g + rg;
                    int nw = (ct * 16 + l15) ^ ((g & 1) << 4);
                    iv_lds[(j * 64 + row) * 64 + nw] = iv;
                }
        #pragma unroll
        for (int rt = 0; rt < 4; ++rt)
            #pragma unroll
            for (int rg = 0; rg < 4; ++rg) {
                float s = rowsum[rt][rg];
                s += __shfl_xor(s, 1); s += __shfl_xor(s, 2);
                s += __shfl_xor(s, 4); s += __shfl_xor(s, 8);
                rowsum[rt][rg] = s;
            }
        if (l15 == 0) {
            #pragma unroll
            for (int rt = 0; rt < 4; ++rt)
                #pragma unroll
                for (int rg = 0; rg < 4; ++rg) {
                    int row = rt * 16 + 4 * g + rg;
                    vrs[row * 8 + j] = rowsum[rt][rg];
                }
        }
    } else {
        // mu-wave: d = y - mu (overlaps var-waves' exp work)
        #pragma unroll
        for (int rt = 0; rt < 4; ++rt)
            #pragma unroll
            for (int ct = 0; ct < 4; ++ct)
                #pragma unroll
                for (int rg = 0; rg < 4; ++rg) {
                    int row = rt * 16 + 4 * g + rg;
                    int bprime = 8 * q + (row >> 3) + j * 8192;
                    float yv = y[(size_t)bprime * 64 + ct * 16 + l15];
                    acc[rt][ct][rg] = yv - acc[rt][ct][rg];
                }
    }
    __syncthreads();

    if (w < 8) {
        float rowsum[4][4];
        #pragma unroll
        for (int rt = 0; rt < 4; ++rt)
            #pragma unroll
            for (int rg = 0; rg < 4; ++rg) rowsum[rt][rg] = 0.0f;
        #pragma unroll
        for (int rt = 0; rt < 4; ++rt)
            #pragma unroll
            for (int ct = 0; ct < 4; ++ct)
                #pragma unroll
                for (int rg = 0; rg < 4; ++rg) {
                    int row = rt * 16 + 4 * g + rg;
                    int nw = (ct * 16 + l15) ^ ((g & 1) << 4);
                    float iv = iv_lds[(j * 64 + row) * 64 + nw];
                    float d = acc[rt][ct][rg];
                    rowsum[rt][rg] = fmaf(d * d, iv, rowsum[rt][rg]);
                }
        #pragma unroll
        for (int rt = 0; rt < 4; ++rt)
            #pragma unroll
            for (int rg = 0; rg < 4; ++rg) {
                float s = rowsum[rt][rg];
                s += __shfl_xor(s, 1); s += __shfl_xor(s, 2);
                s += __shfl_xor(s, 4); s += __shfl_xor(s, 8);
                rowsum[rt][rg] = s;
            }
        if (l15 == 0) {
            #pragma unroll
            for (int rt = 0; rt < 4; ++rt)
                #pragma unroll
                for (int rg = 0; rg < 4; ++rg) {
                    int row = rt * 16 + 4 * g + rg;
                    float lp = -0.5f * (rowsum[rt][rg] + vrs[row * 8 + j]) - HALF_N_LOG2PI;
                    lps[((row >> 3) * 8 + j) * 8 + (row & 7)] = lp;
                }
        }
    }
    __syncthreads();

    // ---------- phase 4: pi network for 64 outputs ----------
    float* tpi = (float*)hs;   // [64][64] fp32 (iv dead)
    {
        int c = t & 63, ob = t >> 6;   // rows {ob, ob+16, ob+32, ob+48}
        float a0 = bp1[c], a1 = a0, a2 = a0, a3 = a0;
        for (int n = 0; n < 64; ++n) {
            float wv = Wp1[n * 64 + c];
            a0 += xp[(ob +  0) * 64 + n] * wv;
            a1 += xp[(ob + 16) * 64 + n] * wv;
            a2 += xp[(ob + 32) * 64 + n] * wv;
            a3 += xp[(ob + 48) * 64 + n] * wv;
        }
        tpi[(ob +  0) * 64 + c] = eluf(a0);
        tpi[(ob + 16) * 64 + c] = eluf(a1);
        tpi[(ob + 32) * 64 + c] = eluf(a2);
        tpi[(ob + 48) * 64 + c] = eluf(a3);
    }
    __syncthreads();
    if (t < 512) {
        int o = t >> 3, k = t & 7;
        float a = bp2[k];
        for (int n = 0; n < 64; ++n) a += tpi[o * 64 + n] * Wp2[n * 8 + k];
        float m = a;
        m = fmaxf(m, __shfl_xor(m, 1));
        m = fmaxf(m, __shfl_xor(m, 2));
        m = fmaxf(m, __shfl_xor(m, 4));
        float e = expf(a - m);
        float sden = e;
        sden += __shfl_xor(sden, 1); sden += __shfl_xor(sden, 2); sden += __shfl_xor(sden, 4);
        float logpi = a - m - logf(sden);
        float v = logpi + lps[o * 8 + k];
        float mv = v;
        mv = fmaxf(mv, __shfl_xor(mv, 1));
        mv = fmaxf(mv, __shfl_xor(mv, 2));
        mv = fmaxf(mv, __shfl_xor(mv, 4));
        float ee = expf(v - mv);
        float ss = ee;
        ss += __shfl_xor(ss, 1); ss += __shfl_xor(ss, 2); ss += __shfl_xor(ss, 4);
        if (k == 0) lses[o] = mv + logf(ss);
    }
    __syncthreads();
    if (t == 0) {
        float p = 0.0f;
        #pragma unroll
        for (int o = 0; o < ROWS; ++o) p += lses[o];
        partials[q] = p;
    }
}

__global__ void reduce_partials(const float* __restrict__ partials, float* __restrict__ out)
{
    __shared__ double red[256];
    int t = threadIdx.x;
    double s = 0.0;
    for (int i = t; i < NBLK; i += 256) s += (double)partials[i];
    red[t] = s;
    __syncthreads();
    for (int w = 128; w > 0; w >>= 1) {
        if (t < w) red[t] += red[t + w];
        __syncthreads();
    }
    if (t == 0) out[0] = (float)(-red[0] / (double)B_TOT);
}

extern "C" void kernel_launch(void* const* d_in, const int* in_sizes, int n_in,
                              void* d_out, int out_size, void* d_ws, size_t ws_size,
                              hipStream_t stream)
{
    const float* x   = (const float*)d_in[0];
    const float* y   = (const float*)d_in[1];
    const float* W1  = (const float*)d_in[2];
    const float* b1  = (const float*)d_in[3];
    const float* W2  = (const float*)d_in[4];
    const float* b2  = (const float*)d_in[5];
    const float* Wp1 = (const float*)d_in[6];
    const float* bp1 = (const float*)d_in[7];
    const float* Wp2 = (const float*)d_in[8];
    const float* bp2 = (const float*)d_in[9];

    char* ws = (char*)d_ws;
    _Float16* W2P = (_Float16*)(ws + WS_W2P);
    _Float16* W1P = (_Float16*)(ws + WS_W1P);
    float* partials = (float*)(ws + WS_PART);

    pack_f16<<<dim3(16, 16), 256, 0, stream>>>(W2, W2P, 1024);
    pack_f16<<<dim3(1, 16), 256, 0, stream>>>(W1, W1P, 64);
    fused_mdn<<<NBLK, THREADS, 0, stream>>>(x, y, W1P, b1, W2P, b2,
                                            Wp1, bp1, Wp2, bp2, partials);
    reduce_partials<<<1, 256, 0, stream>>>(partials, (float*)d_out);
}

// Round 9
// 382.257 us; speedup vs baseline: 1.6777x; 1.4584x over previous
//
#include <hip/hip_runtime.h>
#include <math.h>

typedef __attribute__((ext_vector_type(8))) _Float16 half8;
typedef __attribute__((ext_vector_type(4))) _Float16 half4;
typedef __attribute__((ext_vector_type(4))) float f32x4;

#define B_TOT   65536
#define ROWS    32
#define NBLK    (B_TOT / ROWS)      // 2048
#define THREADS 1024
#define LOG2PI_F 1.8378770664093453f
#define HALF_N_LOG2PI (0.5f * 64.0f * LOG2PI_F)
#define LOG_1EM8 (-18.420680743952367f)

// ws layout (bytes)
#define WS_W2P  0                    // 2 MB fp16 packed
#define WS_W1P  (2*1024*1024)        // 128 KB fp16 packed
#define WS_PART (WS_W1P + 256*1024)

__device__ __forceinline__ float eluf(float v) {
    return v > 0.0f ? v : expm1f(v);
}

// src fp32 [Kd][1024] -> dst fp16 packed [(Kd/32)][1024 n][32 k]
__global__ __launch_bounds__(256)
void pack_f16(const float* __restrict__ src, _Float16* __restrict__ dst, int Kd)
{
    __shared__ float ts[64][65];
    const int t = threadIdx.x;
    const int k0 = blockIdx.x * 64, n0 = blockIdx.y * 64;
    {
        int r = t >> 2, c4 = t & 3;
        for (int i = 0; i < 4; ++i) {
            int cc = i * 4 + c4;
            float4 v = *(const float4*)&src[(size_t)(k0 + r) * 1024 + n0 + cc * 4];
            ts[r][cc*4+0] = v.x; ts[r][cc*4+1] = v.y;
            ts[r][cc*4+2] = v.z; ts[r][cc*4+3] = v.w;
        }
    }
    __syncthreads();
    {
        int n = t >> 2;
        for (int i = 0; i < 4; ++i) {
            int kk = (i * 4 + (t & 3)) * 4;      // 0..60, 4-aligned
            int k = k0 + kk;
            half4 h;
            h.x = (_Float16)ts[kk+0][n];
            h.y = (_Float16)ts[kk+1][n];
            h.z = (_Float16)ts[kk+2][n];
            h.w = (_Float16)ts[kk+3][n];
            size_t off = (size_t)(k >> 5) * 32768 + (size_t)(n0 + n) * 32 + (k & 31);
            *(half4*)&dst[off] = h;
        }
    }
}

// 64-VGPR budget by design (acc 32 + frags 24): hipcc pins 1024-thread kernels at 64 arch VGPRs
// (measured rounds 5-8). LDS ~78 KB => 2 blocks/CU at 8 waves/SIMD.
__global__ __launch_bounds__(THREADS)
void fused_mdn(const float* __restrict__ x, const float* __restrict__ y,
               const _Float16* __restrict__ W1P, const float* __restrict__ b1,
               const _Float16* __restrict__ W2P, const float* __restrict__ b2,
               const float* __restrict__ Wp1, const float* __restrict__ bp1,
               const float* __restrict__ Wp2, const float* __restrict__ bp2,
               float* __restrict__ partials)
{
    __shared__ __align__(16) _Float16 hs[ROWS * 1024];  // 64 KB: h fp16 -> iv fp32 -> tpi fp32
    __shared__ __align__(16) float    xp[ROWS * 64];    // 8 KB: pi-x rows
    __shared__ __align__(16) _Float16 xs[ROWS * 64];    // 4 KB: x fp16 swizzled
    __shared__ float lps[256];                          // 1 KB
    __shared__ float vrs[256];                          // 1 KB
    __shared__ float lses[ROWS];                        // 128 B

    const int t   = threadIdx.x;
    const int q   = blockIdx.x;
    const int w   = t >> 6;      // 0..15, wave owns cols [w*64, w*64+64)
    const int l   = t & 63;
    const int g   = l >> 4;
    const int l15 = l & 15;

    // ---------- phase 0: stage x rows (fp16, swizzled) + xp rows ----------
    if (t < 512) {
        const float4* x4 = (const float4*)x;
        int r = t >> 4, c = t & 15;
        float4 v = x4[(size_t)(q * ROWS + r) * 16 + c];
        float vv[4] = {v.x, v.y, v.z, v.w};
        #pragma unroll
        for (int i = 0; i < 4; ++i) {
            int col = c * 4 + i;
            xs[r * 64 + (col ^ ((r & 7) << 3))] = (_Float16)vv[i];
        }
        // pi-x rows: output o -> b' = 4q + (o>>3) + (o&7)*8192
        int bprime = 4 * q + (r >> 3) + (r & 7) * 8192;
        ((float4*)xp)[r * 16 + c] = x4[(size_t)bprime * 16 + c];
    }
    __syncthreads();

    f32x4 acc[2][4];

    // ---------- phase 1: h = elu(x @ W1 + b1), fp16 MFMA ----------
    #pragma unroll
    for (int ct = 0; ct < 4; ++ct) {
        float bv = b1[w * 64 + ct * 16 + l15];
        acc[0][ct] = (f32x4){bv, bv, bv, bv};
        acc[1][ct] = (f32x4){bv, bv, bv, bv};
    }
    #pragma unroll
    for (int k0 = 0; k0 < 64; k0 += 32) {
        half8 bF[4];
        #pragma unroll
        for (int ct = 0; ct < 4; ++ct) {
            size_t off = (size_t)(k0 >> 5) * 32768 + (size_t)(w * 64 + ct * 16 + l15) * 32 + 8 * g;
            bF[ct] = *(const half8*)&W1P[off];
        }
        half8 aF[2];
        #pragma unroll
        for (int rt = 0; rt < 2; ++rt) {
            int row = rt * 16 + l15;
            aF[rt] = *(const half8*)&xs[row * 64 + ((k0 + 8 * g) ^ ((row & 7) << 3))];
        }
        #pragma unroll
        for (int ct = 0; ct < 4; ++ct)
            #pragma unroll
            for (int rt = 0; rt < 2; ++rt)
                acc[rt][ct] = __builtin_amdgcn_mfma_f32_16x16x32_f16(aF[rt], bF[ct], acc[rt][ct], 0, 0, 0);
    }
    // epilogue: ELU -> fp16 -> hs (swizzled)
    #pragma unroll
    for (int rt = 0; rt < 2; ++rt)
        #pragma unroll
        for (int ct = 0; ct < 4; ++ct)
            #pragma unroll
            for (int rg = 0; rg < 4; ++rg) {
                float v = eluf(acc[rt][ct][rg]);
                int row = rt * 16 + 4 * g + rg;
                int col = w * 64 + ct * 16 + l15;
                hs[row * 1024 + (col ^ ((row & 7) << 3))] = (_Float16)v;
            }
    __syncthreads();

    // ---------- phase 2: fhatx = h @ W2 + b2, fp16 MFMA ----------
    #pragma unroll
    for (int ct = 0; ct < 4; ++ct) {
        float bv = b2[w * 64 + ct * 16 + l15];
        acc[0][ct] = (f32x4){bv, bv, bv, bv};
        acc[1][ct] = (f32x4){bv, bv, bv, bv};
    }
    for (int k0 = 0; k0 < 1024; k0 += 32) {
        half8 bF[4];
        #pragma unroll
        for (int ct = 0; ct < 4; ++ct) {
            size_t off = (size_t)(k0 >> 5) * 32768 + (size_t)(w * 64 + ct * 16 + l15) * 32 + 8 * g;
            bF[ct] = *(const half8*)&W2P[off];
        }
        half8 aF[2];
        #pragma unroll
        for (int rt = 0; rt < 2; ++rt) {
            int row = rt * 16 + l15;
            aF[rt] = *(const half8*)&hs[row * 1024 + ((k0 + 8 * g) ^ ((row & 7) << 3))];
        }
        #pragma unroll
        for (int ct = 0; ct < 4; ++ct)
            #pragma unroll
            for (int rt = 0; rt < 2; ++rt)
                acc[rt][ct] = __builtin_amdgcn_mfma_f32_16x16x32_f16(aF[rt], bF[ct], acc[rt][ct], 0, 0, 0);
    }
    __syncthreads();   // all hs reads done; hs region becomes iv (fp32)

    // ---------- phase 3: MDN log-prob, in-register ----------
    // wave w<8: mu[mix j=w][rows 0:32][n 0:64]; wave w>=8: var_raw for mix j=w-8.
    const int j = w & 7;
    float* iv_lds = (float*)hs;     // [8 mix][32 row][64 n] fp32 = 64 KB

    if (w >= 8) {
        float rowsum[2][4];
        #pragma unroll
        for (int rt = 0; rt < 2; ++rt)
            #pragma unroll
            for (int rg = 0; rg < 4; ++rg) rowsum[rt][rg] = 0.0f;
        #pragma unroll
        for (int rt = 0; rt < 2; ++rt)
            #pragma unroll
            for (int ct = 0; ct < 4; ++ct)
                #pragma unroll
                for (int rg = 0; rg < 4; ++rg) {
                    float vr = acc[rt][ct][rg];
                    float vre = fmaxf(vr, LOG_1EM8);
                    float iv = (vr >= LOG_1EM8) ? expf(-vr) : 1e8f;
                    rowsum[rt][rg] += vre;
                    int row = rt * 16 + 4 * g + rg;
                    int nw = (ct * 16 + l15) ^ ((g & 1) << 4);
                    iv_lds[(j * 32 + row) * 64 + nw] = iv;
                }
        #pragma unroll
        for (int rt = 0; rt < 2; ++rt)
            #pragma unroll
            for (int rg = 0; rg < 4; ++rg) {
                float s = rowsum[rt][rg];
                s += __shfl_xor(s, 1); s += __shfl_xor(s, 2);
                s += __shfl_xor(s, 4); s += __shfl_xor(s, 8);
                rowsum[rt][rg] = s;
            }
        if (l15 == 0) {
            #pragma unroll
            for (int rt = 0; rt < 2; ++rt)
                #pragma unroll
                for (int rg = 0; rg < 4; ++rg) {
                    int row = rt * 16 + 4 * g + rg;
                    vrs[row * 8 + j] = rowsum[rt][rg];
                }
        }
    } else {
        // mu-wave: d = y - mu (overlaps var-waves' exp work)
        #pragma unroll
        for (int rt = 0; rt < 2; ++rt)
            #pragma unroll
            for (int ct = 0; ct < 4; ++ct)
                #pragma unroll
                for (int rg = 0; rg < 4; ++rg) {
                    int row = rt * 16 + 4 * g + rg;
                    int bprime = 4 * q + (row >> 3) + j * 8192;
                    float yv = y[(size_t)bprime * 64 + ct * 16 + l15];
                    acc[rt][ct][rg] = yv - acc[rt][ct][rg];
                }
    }
    __syncthreads();

    if (w < 8) {
        float rowsum[2][4];
        #pragma unroll
        for (int rt = 0; rt < 2; ++rt)
            #pragma unroll
            for (int rg = 0; rg < 4; ++rg) rowsum[rt][rg] = 0.0f;
        #pragma unroll
        for (int rt = 0; rt < 2; ++rt)
            #pragma unroll
            for (int ct = 0; ct < 4; ++ct)
                #pragma unroll
                for (int rg = 0; rg < 4; ++rg) {
                    int row = rt * 16 + 4 * g + rg;
                    int nw = (ct * 16 + l15) ^ ((g & 1) << 4);
                    float iv = iv_lds[(j * 32 + row) * 64 + nw];
                    float d = acc[rt][ct][rg];
                    rowsum[rt][rg] = fmaf(d * d, iv, rowsum[rt][rg]);
                }
        #pragma unroll
        for (int rt = 0; rt < 2; ++rt)
            #pragma unroll
            for (int rg = 0; rg < 4; ++rg) {
                float s = rowsum[rt][rg];
                s += __shfl_xor(s, 1); s += __shfl_xor(s, 2);
                s += __shfl_xor(s, 4); s += __shfl_xor(s, 8);
                rowsum[rt][rg] = s;
            }
        if (l15 == 0) {
            #pragma unroll
            for (int rt = 0; rt < 2; ++rt)
                #pragma unroll
                for (int rg = 0; rg < 4; ++rg) {
                    int row = rt * 16 + 4 * g + rg;
                    float lp = -0.5f * (rowsum[rt][rg] + vrs[row * 8 + j]) - HALF_N_LOG2PI;
                    lps[((row >> 3) * 8 + j) * 8 + (row & 7)] = lp;
                }
        }
    }
    __syncthreads();

    // ---------- phase 4: pi network for 32 outputs ----------
    float* tpi = (float*)hs;   // [32][64] fp32 (iv dead)
    {
        int c = t & 63, ob = t >> 6;   // ob 0..15, rows {ob, ob+16}
        float a0 = bp1[c], a1 = a0;
        for (int n = 0; n < 64; ++n) {
            float wv = Wp1[n * 64 + c];
            a0 += xp[ob * 64 + n] * wv;
            a1 += xp[(ob + 16) * 64 + n] * wv;
        }
        tpi[ob * 64 + c] = eluf(a0);
        tpi[(ob + 16) * 64 + c] = eluf(a1);
    }
    __syncthreads();
    if (t < 256) {
        int o = t >> 3, k = t & 7;
        float a = bp2[k];
        for (int n = 0; n < 64; ++n) a += tpi[o * 64 + n] * Wp2[n * 8 + k];
        float m = a;
        m = fmaxf(m, __shfl_xor(m, 1));
        m = fmaxf(m, __shfl_xor(m, 2));
        m = fmaxf(m, __shfl_xor(m, 4));
        float e = expf(a - m);
        float sden = e;
        sden += __shfl_xor(sden, 1); sden += __shfl_xor(sden, 2); sden += __shfl_xor(sden, 4);
        float logpi = a - m - logf(sden);
        float v = logpi + lps[o * 8 + k];
        float mv = v;
        mv = fmaxf(mv, __shfl_xor(mv, 1));
        mv = fmaxf(mv, __shfl_xor(mv, 2));
        mv = fmaxf(mv, __shfl_xor(mv, 4));
        float ee = expf(v - mv);
        float ss = ee;
        ss += __shfl_xor(ss, 1); ss += __shfl_xor(ss, 2); ss += __shfl_xor(ss, 4);
        if (k == 0) lses[o] = mv + logf(ss);
    }
    __syncthreads();
    if (t == 0) {
        float p = 0.0f;
        #pragma unroll
        for (int o = 0; o < ROWS; ++o) p += lses[o];
        partials[q] = p;
    }
}

__global__ void reduce_partials(const float* __restrict__ partials, float* __restrict__ out)
{
    __shared__ double red[256];
    int t = threadIdx.x;
    double s = 0.0;
    for (int i = t; i < NBLK; i += 256) s += (double)partials[i];
    red[t] = s;
    __syncthreads();
    for (int w = 128; w > 0; w >>= 1) {
        if (t < w) red[t] += red[t + w];
        __syncthreads();
    }
    if (t == 0) out[0] = (float)(-red[0] / (double)B_TOT);
}

extern "C" void kernel_launch(void* const* d_in, const int* in_sizes, int n_in,
                              void* d_out, int out_size, void* d_ws, size_t ws_size,
                              hipStream_t stream)
{
    const float* x   = (const float*)d_in[0];
    const float* y   = (const float*)d_in[1];
    const float* W1  = (const float*)d_in[2];
    const float* b1  = (const float*)d_in[3];
    const float* W2  = (const float*)d_in[4];
    const float* b2  = (const float*)d_in[5];
    const float* Wp1 = (const float*)d_in[6];
    const float* bp1 = (const float*)d_in[7];
    const float* Wp2 = (const float*)d_in[8];
    const float* bp2 = (const float*)d_in[9];

    char* ws = (char*)d_ws;
    _Float16* W2P = (_Float16*)(ws + WS_W2P);
    _Float16* W1P = (_Float16*)(ws + WS_W1P);
    float* partials = (float*)(ws + WS_PART);

    pack_f16<<<dim3(16, 16), 256, 0, stream>>>(W2, W2P, 1024);
    pack_f16<<<dim3(1, 16), 256, 0, stream>>>(W1, W1P, 64);
    fused_mdn<<<NBLK, THREADS, 0, stream>>>(x, y, W1P, b1, W2P, b2,
                                            Wp1, bp1, Wp2, bp2, partials);
    reduce_partials<<<1, 256, 0, stream>>>(partials, (float*)d_out);
}